// Round 4
// baseline (128.203 us; speedup 1.0000x reference)
//
#include <hip/hip_runtime.h>

#define D 256

typedef __attribute__((ext_vector_type(8))) _Float16 f16x8;
typedef __attribute__((ext_vector_type(8))) short    s16x8;
typedef __attribute__((ext_vector_type(4))) float    f4_t;
typedef unsigned long long ull;

// ---- fused: fp32 -> fp16 panel-permute + numpy-pairwise row sum-of-squares --
// panel: element (row,k) -> (row>>4)*4096 + (s*64 + chunk*16 + rr)*8 + e
//   s=k>>5, chunk=(k&31)>>3, rr=row&15, e=k&7. Wave frag read = base + lane*8.
__global__ __launch_bounds__(256) void conv_perm(const float* __restrict__ in,
    short* __restrict__ out, float* __restrict__ sq) {
    __shared__ float tile[16 * 264];
    const int t = threadIdx.x;
    const int p = blockIdx.x;
    const float* src = in + (size_t)p * 16 * 256;
#pragma unroll
    for (int it = 0; it < 4; ++it) {
        int idx = it * 256 + t;
        int row = idx >> 6, c4 = idx & 63;
        float4 v = *(const float4*)(src + row * 256 + c4 * 4);
        *(float4*)(tile + row * 264 + c4 * 4) = v;
    }
    __syncthreads();
    // rowsq: 16 threads/row, numpy pairwise order (8 strided accs + fixed tree)
    {
        int row = t >> 4, lane = t & 15;
        int b = lane >> 3, j = lane & 7;
        const float* q = tile + row * 264 + b * 128 + j;
        float r = 0.f;
        {
#pragma clang fp contract(off)
            for (int i = 0; i < 16; ++i) { float v = q[8 * i]; float s2 = v * v; r = r + s2; }
        }
        r += __shfl_xor(r, 1); r += __shfl_xor(r, 2);
        r += __shfl_xor(r, 4); r += __shfl_xor(r, 8);
        if (lane == 0) sq[p * 16 + row] = r;
    }
    // permute + fp16 convert (RTE)
#pragma unroll
    for (int jj = 0; jj < 2; ++jj) {
        int sl = jj * 256 + t;
        int s = sl >> 6, chunk = (sl >> 4) & 3, rr = sl & 15;
        const float* q = tile + rr * 264 + s * 32 + chunk * 8;
        s16x8 h8;
#pragma unroll
        for (int e = 0; e < 8; ++e) {
            _Float16 hv = (_Float16)q[e];
            h8[e] = (short)__builtin_bit_cast(unsigned short, hv);
        }
        *(s16x8*)(out + (size_t)p * 4096 + (size_t)sl * 8) = h8;
    }
}

// ---- main: 1-pass fp16 xe GEMM + exact-64-bit-key top-2 per 256-code group --
// Block: 32 rows x 512 codes (half h). 4 waves x 128 codes. A in LDS once;
// B register-double-buffered from L1/L2. Full-unrolled s-loop (static bufs).
__global__ __launch_bounds__(256, 2) void vq_gemm(
    const short* __restrict__ Xh, const short* __restrict__ Eh,
    const float* __restrict__ e2, int* __restrict__ cand) {
    __shared__ short As[8192];                  // 32 rows x 256 k fp16 = 16 KB
    const int tid = threadIdx.x;
    const int l = tid & 63;
    const int w = tid >> 6;
    const int rb = blockIdx.x >> 1;
    const int h = blockIdx.x & 1;
    const int R0 = rb * 32;

#pragma unroll
    for (int jj = 0; jj < 4; ++jj)
        *(s16x8*)(As + jj * 2048 + tid * 8) =
            *(const s16x8*)(Xh + (size_t)(R0 >> 4) * 4096 + jj * 2048 + tid * 8);
    __syncthreads();

    const f16x8* Bv = (const f16x8*)Eh;
    const f16x8* Av = (const f16x8*)As;
    const int pc0 = (h * 512 + w * 128) >> 4;   // first of 8 B panels

    f4_t acc[2][8];
#pragma unroll
    for (int m = 0; m < 2; ++m)
#pragma unroll
        for (int n = 0; n < 8; ++n) { f4_t z = {0.f, 0.f, 0.f, 0.f}; acc[m][n] = z; }

    f16x8 bb[2][8], aa[2][2];
#pragma unroll
    for (int n = 0; n < 8; ++n) bb[0][n] = Bv[((pc0 + n) * 8 + 0) * 64 + l];
#pragma unroll
    for (int m = 0; m < 2; ++m) aa[0][m] = Av[m * 512 + 0 * 64 + l];

#pragma unroll
    for (int s = 0; s < 8; ++s) {
        const int cur = s & 1, nxt = cur ^ 1;
        if (s < 7) {
#pragma unroll
            for (int n = 0; n < 8; ++n)
                bb[nxt][n] = Bv[((pc0 + n) * 8 + s + 1) * 64 + l];
#pragma unroll
            for (int m = 0; m < 2; ++m)
                aa[nxt][m] = Av[m * 512 + (s + 1) * 64 + l];
        }
#pragma unroll
        for (int n = 0; n < 8; ++n)
#pragma unroll
            for (int m = 0; m < 2; ++m)
                acc[m][n] = __builtin_amdgcn_mfma_f32_16x16x32_f16(
                    aa[cur][m], bb[cur][n], acc[m][n], 0, 0, 0);
    }

    // exact 64-bit keys: v = 0.5*e2 + 256 - xe (>0), key = bits(v)<<32 | code
    ull k1[2][4], k2[2][4];
#pragma unroll
    for (int m = 0; m < 2; ++m)
#pragma unroll
        for (int r = 0; r < 4; ++r) { k1[m][r] = ~0ull; k2[m][r] = ~0ull; }
#pragma unroll
    for (int n = 0; n < 8; ++n) {
        int code = h * 512 + w * 128 + n * 16 + (l & 15);
        float e2b = 0.5f * e2[code] + 256.0f;
#pragma unroll
        for (int m = 0; m < 2; ++m)
#pragma unroll
            for (int r = 0; r < 4; ++r) {
                float v = e2b - acc[m][n][r];
                ull key = ((ull)__builtin_bit_cast(unsigned int, v) << 32) | (unsigned int)code;
                ull mx = k1[m][r] > key ? k1[m][r] : key;
                k1[m][r] = k1[m][r] < key ? k1[m][r] : key;
                k2[m][r] = k2[m][r] < mx ? k2[m][r] : mx;
            }
    }
    // top-2 merge across the 16 lanes sharing each row
#pragma unroll
    for (int m = 0; m < 2; ++m)
#pragma unroll
        for (int r = 0; r < 4; ++r) {
            ull a = k1[m][r], b = k2[m][r];
#pragma unroll
            for (int msk = 1; msk < 16; msk <<= 1) {
                ull oa = __shfl_xor(a, msk);
                ull ob = __shfl_xor(b, msk);
                ull hi_ = a > oa ? a : oa;
                a = a < oa ? a : oa;
                b = b < ob ? b : ob;
                b = b < hi_ ? b : hi_;
            }
            k1[m][r] = a; k2[m][r] = b;
        }
    // merge wave pairs (0,1) and (2,3): top-2 per 256-code group -> 4 cand/half
    __syncthreads();
    ull* mrg = (ull*)As;                        // [32 rows][4 waves][2]
    if ((l & 15) == 0) {
#pragma unroll
        for (int m = 0; m < 2; ++m)
#pragma unroll
            for (int r = 0; r < 4; ++r) {
                int rloc = m * 16 + (l >> 4) * 4 + r;
                mrg[(rloc * 4 + w) * 2 + 0] = k1[m][r];
                mrg[(rloc * 4 + w) * 2 + 1] = k2[m][r];
            }
    }
    __syncthreads();
    if (tid < 64) {
        int row = tid >> 1, pr = tid & 1;
        ull a1 = mrg[(row * 4 + pr * 2) * 2 + 0];
        ull a2 = mrg[(row * 4 + pr * 2) * 2 + 1];
        ull b1 = mrg[(row * 4 + pr * 2 + 1) * 2 + 0];
        ull b2 = mrg[(row * 4 + pr * 2 + 1) * 2 + 1];
        ull c1 = a1 < b1 ? a1 : b1;
        ull t  = a1 > b1 ? a1 : b1;
        ull mn = a2 < b2 ? a2 : b2;
        ull c2 = t < mn ? t : mn;
        int2 o; o.x = (int)(c1 & 1023ull); o.y = (int)(c2 & 1023ull);
        *(int2*)(cand + (size_t)(R0 + row) * 8 + h * 4 + pr * 2) = o;
    }
}

// ---- exact fp32 recheck of 8 candidates (ref formula + tie-break) + gather --
__global__ __launch_bounds__(256) void vq_decide(const float* __restrict__ x,
    const float* __restrict__ cb, const int* __restrict__ cand,
    const float* __restrict__ x2, const float* __restrict__ e2,
    float* __restrict__ outq, float* __restrict__ outi) {
    const int w = threadIdx.x >> 6, l = threadIdx.x & 63;
    const int row = blockIdx.x * 4 + w;
    const int o = l >> 3, j = l & 7;
    const int c = cand[(size_t)row * 8 + o];
    const float4* xr = (const float4*)(x + (size_t)row * D);
    const float4* er = (const float4*)(cb + (size_t)c * D);
    float xe = 0.f;
#pragma unroll
    for (int i = 0; i < 8; ++i) {
        float4 xv = xr[j * 8 + i], ev = er[j * 8 + i];
        xe = fmaf(xv.x, ev.x, xe); xe = fmaf(xv.y, ev.y, xe);
        xe = fmaf(xv.z, ev.z, xe); xe = fmaf(xv.w, ev.w, xe);
    }
    xe += __shfl_xor(xe, 1); xe += __shfl_xor(xe, 2); xe += __shfl_xor(xe, 4);
    float s0 = x2[row] + e2[c];                 // ref order: (x2 + e2) first
    float dist = s0 - 2.f * xe;                 // then - 2*xe
    float best = 3.4e38f; int bi = 0x7fffffff;
#pragma unroll
    for (int oq = 0; oq < 8; ++oq) {
        float dd = __shfl(dist, oq * 8);
        int   ii = __shfl(c,    oq * 8);
        if (dd < best || (dd == best && ii < bi)) { best = dd; bi = ii; }
    }
    float4 v = ((const float4*)(cb + (size_t)bi * D))[l];
    ((float4*)(outq + (size_t)row * D))[l] = v;
    if (l == 0) outi[row] = (float)bi;
}

extern "C" void kernel_launch(void* const* d_in, const int* in_sizes, int n_in,
                              void* d_out, int out_size, void* d_ws, size_t ws_size,
                              hipStream_t stream) {
    const float* x  = (const float*)d_in[0];
    const float* cb = (const float*)d_in[1];
    const int N  = in_sizes[0] / D;   // 32768
    const int Kc = in_sizes[1] / D;   // 1024

    float* outq = (float*)d_out;
    float* outi = outq + (size_t)N * D;

    const size_t needX = (size_t)N * D * 2;                       // fp16 X, 16 MB
    const size_t needS = (size_t)Kc * D * 2 + (size_t)Kc * 4
                       + (size_t)N * 4 + (size_t)N * 8 * 4;       // ~1.7 MB

    short* Xh; char* small;
    if (ws_size >= needX + needS) {
        Xh = (short*)d_ws;
        small = (char*)d_ws + needX;
    } else {
        // Xh lives in d_out[0,16MB). gemm reads it; vq_decide overwrites that
        // region with outq only after gemm completes (stream order). outi is
        // the last 128 KB of d_out -- no overlap.
        Xh = (short*)d_out;
        small = (char*)d_ws;
    }
    short* Eh  = (short*)small;
    float* e2  = (float*)(Eh + (size_t)Kc * D);
    float* x2  = e2 + Kc;
    int*  cand = (int*)(x2 + N);

    conv_perm<<<N / 16, 256, 0, stream>>>(x, Xh, x2);
    conv_perm<<<Kc / 16, 256, 0, stream>>>(cb, Eh, e2);
    vq_gemm<<<(N / 32) * 2, 256, 0, stream>>>(Xh, Eh, e2, cand);
    vq_decide<<<N / 4, 256, 0, stream>>>(x, cb, cand, x2, e2, outq, outi);
}

// Round 5
// 82.734 us; speedup vs baseline: 1.5496x; 1.5496x over previous
//
#include <hip/hip_runtime.h>

#define D 256

typedef __attribute__((ext_vector_type(8))) _Float16 f16x8;
typedef __attribute__((ext_vector_type(8))) short    s16x8;
typedef __attribute__((ext_vector_type(4))) float    f4_t;
typedef unsigned long long ull;

// ---- fused: fp32 -> fp16 panel-permute + numpy-pairwise row sum-of-squares --
// panel: element (row,k) -> (row>>4)*4096 + (s*64 + chunk*16 + rr)*8 + e
//   s=k>>5, chunk=(k&31)>>3, rr=row&15, e=k&7. Wave frag read = base + lane*8.
__global__ __launch_bounds__(256) void conv_perm(const float* __restrict__ in,
    short* __restrict__ out, float* __restrict__ sq) {
    __shared__ float tile[16 * 264];
    const int t = threadIdx.x;
    const int p = blockIdx.x;
    const float* src = in + (size_t)p * 16 * 256;
#pragma unroll
    for (int it = 0; it < 4; ++it) {
        int idx = it * 256 + t;
        int row = idx >> 6, c4 = idx & 63;
        float4 v = *(const float4*)(src + row * 256 + c4 * 4);
        *(float4*)(tile + row * 264 + c4 * 4) = v;
    }
    __syncthreads();
    // rowsq: 16 threads/row, numpy pairwise order (8 strided accs + fixed tree)
    {
        int row = t >> 4, lane = t & 15;
        int b = lane >> 3, j = lane & 7;
        const float* q = tile + row * 264 + b * 128 + j;
        float r = 0.f;
        {
#pragma clang fp contract(off)
            for (int i = 0; i < 16; ++i) { float v = q[8 * i]; float s2 = v * v; r = r + s2; }
        }
        r += __shfl_xor(r, 1); r += __shfl_xor(r, 2);
        r += __shfl_xor(r, 4); r += __shfl_xor(r, 8);
        if (lane == 0) sq[p * 16 + row] = r;
    }
    // permute + fp16 convert (RTE)
#pragma unroll
    for (int jj = 0; jj < 2; ++jj) {
        int sl = jj * 256 + t;
        int s = sl >> 6, chunk = (sl >> 4) & 3, rr = sl & 15;
        const float* q = tile + rr * 264 + s * 32 + chunk * 8;
        s16x8 h8;
#pragma unroll
        for (int e = 0; e < 8; ++e) {
            _Float16 hv = (_Float16)q[e];
            h8[e] = (short)__builtin_bit_cast(unsigned short, hv);
        }
        *(s16x8*)(out + (size_t)p * 4096 + (size_t)sl * 8) = h8;
    }
}

// ---- main: 1-pass fp16 xe GEMM + exact-64-bit-key top-2 per 256-code group --
// Block: 32 rows x 512 codes (half h). 4 waves x 128 codes. A in LDS once;
// B register-double-buffered from L1/L2. Full-unrolled s-loop (static bufs).
__global__ __launch_bounds__(256, 2) void vq_gemm(
    const short* __restrict__ Xh, const short* __restrict__ Eh,
    const float* __restrict__ e2, int* __restrict__ cand) {
    __shared__ short As[8192];                  // 32 rows x 256 k fp16 = 16 KB
    const int tid = threadIdx.x;
    const int l = tid & 63;
    const int w = tid >> 6;
    const int rb = blockIdx.x >> 1;
    const int h = blockIdx.x & 1;
    const int R0 = rb * 32;

#pragma unroll
    for (int jj = 0; jj < 4; ++jj)
        *(s16x8*)(As + jj * 2048 + tid * 8) =
            *(const s16x8*)(Xh + (size_t)(R0 >> 4) * 4096 + jj * 2048 + tid * 8);
    __syncthreads();

    const f16x8* Bv = (const f16x8*)Eh;
    const f16x8* Av = (const f16x8*)As;
    const int pc0 = (h * 512 + w * 128) >> 4;   // first of 8 B panels

    f4_t acc[2][8];
#pragma unroll
    for (int m = 0; m < 2; ++m)
#pragma unroll
        for (int n = 0; n < 8; ++n) { f4_t z = {0.f, 0.f, 0.f, 0.f}; acc[m][n] = z; }

    f16x8 bb[2][8], aa[2][2];
#pragma unroll
    for (int n = 0; n < 8; ++n) bb[0][n] = Bv[((pc0 + n) * 8 + 0) * 64 + l];
#pragma unroll
    for (int m = 0; m < 2; ++m) aa[0][m] = Av[m * 512 + 0 * 64 + l];

#pragma unroll
    for (int s = 0; s < 8; ++s) {
        const int cur = s & 1, nxt = cur ^ 1;
        if (s < 7) {
#pragma unroll
            for (int n = 0; n < 8; ++n)
                bb[nxt][n] = Bv[((pc0 + n) * 8 + s + 1) * 64 + l];
#pragma unroll
            for (int m = 0; m < 2; ++m)
                aa[nxt][m] = Av[m * 512 + (s + 1) * 64 + l];
        }
#pragma unroll
        for (int n = 0; n < 8; ++n)
#pragma unroll
            for (int m = 0; m < 2; ++m)
                acc[m][n] = __builtin_amdgcn_mfma_f32_16x16x32_f16(
                    aa[cur][m], bb[cur][n], acc[m][n], 0, 0, 0);
    }

    // exact 64-bit keys: v = 0.5*e2 + 256 - xe (>0), key = bits(v)<<32 | code
    ull k1[2][4], k2[2][4];
#pragma unroll
    for (int m = 0; m < 2; ++m)
#pragma unroll
        for (int r = 0; r < 4; ++r) { k1[m][r] = ~0ull; k2[m][r] = ~0ull; }
#pragma unroll
    for (int n = 0; n < 8; ++n) {
        int code = h * 512 + w * 128 + n * 16 + (l & 15);
        float e2b = 0.5f * e2[code] + 256.0f;
#pragma unroll
        for (int m = 0; m < 2; ++m)
#pragma unroll
            for (int r = 0; r < 4; ++r) {
                float v = e2b - acc[m][n][r];
                ull key = ((ull)__builtin_bit_cast(unsigned int, v) << 32) | (unsigned int)code;
                ull mx = k1[m][r] > key ? k1[m][r] : key;
                k1[m][r] = k1[m][r] < key ? k1[m][r] : key;
                k2[m][r] = k2[m][r] < mx ? k2[m][r] : mx;
            }
    }
    // top-2 merge across the 16 lanes sharing each row
#pragma unroll
    for (int m = 0; m < 2; ++m)
#pragma unroll
        for (int r = 0; r < 4; ++r) {
            ull a = k1[m][r], b = k2[m][r];
#pragma unroll
            for (int msk = 1; msk < 16; msk <<= 1) {
                ull oa = __shfl_xor(a, msk);
                ull ob = __shfl_xor(b, msk);
                ull hi_ = a > oa ? a : oa;
                a = a < oa ? a : oa;
                b = b < ob ? b : ob;
                b = b < hi_ ? b : hi_;
            }
            k1[m][r] = a; k2[m][r] = b;
        }
    // merge wave pairs (0,1) and (2,3): top-2 per 256-code group -> 4 cand/half
    __syncthreads();
    ull* mrg = (ull*)As;                        // [32 rows][4 waves][2]
    if ((l & 15) == 0) {
#pragma unroll
        for (int m = 0; m < 2; ++m)
#pragma unroll
            for (int r = 0; r < 4; ++r) {
                int rloc = m * 16 + (l >> 4) * 4 + r;
                mrg[(rloc * 4 + w) * 2 + 0] = k1[m][r];
                mrg[(rloc * 4 + w) * 2 + 1] = k2[m][r];
            }
    }
    __syncthreads();
    if (tid < 64) {
        int row = tid >> 1, pr = tid & 1;
        ull a1 = mrg[(row * 4 + pr * 2) * 2 + 0];
        ull a2 = mrg[(row * 4 + pr * 2) * 2 + 1];
        ull b1 = mrg[(row * 4 + pr * 2 + 1) * 2 + 0];
        ull b2 = mrg[(row * 4 + pr * 2 + 1) * 2 + 1];
        ull c1 = a1 < b1 ? a1 : b1;
        ull t  = a1 > b1 ? a1 : b1;
        ull mn = a2 < b2 ? a2 : b2;
        ull c2 = t < mn ? t : mn;
        int2 o; o.x = (int)(c1 & 1023ull); o.y = (int)(c2 & 1023ull);
        *(int2*)(cand + (size_t)(R0 + row) * 8 + h * 4 + pr * 2) = o;
    }
}

// ---- exact fp32 recheck of 8 candidates (ref formula + tie-break) + gather --
// Coalesced: within each 8-lane candidate group, lane j reads float4 (i*8+j)
// -> one contiguous 128B segment per iteration (x segments shared via L1).
__global__ __launch_bounds__(256) void vq_decide(const float* __restrict__ x,
    const float* __restrict__ cb, const int* __restrict__ cand,
    const float* __restrict__ x2, const float* __restrict__ e2,
    float* __restrict__ outq, float* __restrict__ outi) {
    const int w = threadIdx.x >> 6, l = threadIdx.x & 63;
    const int row = blockIdx.x * 4 + w;
    const int o = l >> 3, j = l & 7;
    const int c = cand[(size_t)row * 8 + o];
    const float4* xr = (const float4*)(x + (size_t)row * D);
    const float4* er = (const float4*)(cb + (size_t)c * D);
    float xe = 0.f;
#pragma unroll
    for (int i = 0; i < 8; ++i) {
        float4 xv = xr[i * 8 + j], ev = er[i * 8 + j];
        xe = fmaf(xv.x, ev.x, xe); xe = fmaf(xv.y, ev.y, xe);
        xe = fmaf(xv.z, ev.z, xe); xe = fmaf(xv.w, ev.w, xe);
    }
    xe += __shfl_xor(xe, 1); xe += __shfl_xor(xe, 2); xe += __shfl_xor(xe, 4);
    float s0 = x2[row] + e2[c];                 // ref order: (x2 + e2) first
    float dist = s0 - 2.f * xe;                 // then - 2*xe
    float best = 3.4e38f; int bi = 0x7fffffff;
#pragma unroll
    for (int oq = 0; oq < 8; ++oq) {
        float dd = __shfl(dist, oq * 8);
        int   ii = __shfl(c,    oq * 8);
        if (dd < best || (dd == best && ii < bi)) { best = dd; bi = ii; }
    }
    float4 v = ((const float4*)(cb + (size_t)bi * D))[l];
    ((float4*)(outq + (size_t)row * D))[l] = v;
    if (l == 0) outi[row] = (float)bi;
}

extern "C" void kernel_launch(void* const* d_in, const int* in_sizes, int n_in,
                              void* d_out, int out_size, void* d_ws, size_t ws_size,
                              hipStream_t stream) {
    const float* x  = (const float*)d_in[0];
    const float* cb = (const float*)d_in[1];
    const int N  = in_sizes[0] / D;   // 32768
    const int Kc = in_sizes[1] / D;   // 1024

    float* outq = (float*)d_out;
    float* outi = outq + (size_t)N * D;

    const size_t needX = (size_t)N * D * 2;                       // fp16 X, 16 MB
    const size_t needS = (size_t)Kc * D * 2 + (size_t)Kc * 4
                       + (size_t)N * 4 + (size_t)N * 8 * 4;       // ~1.7 MB

    short* Xh; char* small;
    if (ws_size >= needX + needS) {
        Xh = (short*)d_ws;
        small = (char*)d_ws + needX;
    } else {
        // Xh lives in d_out[0,16MB). gemm reads it; vq_decide overwrites that
        // region with outq only after gemm completes (stream order). outi is
        // the last 128 KB of d_out -- no overlap.
        Xh = (short*)d_out;
        small = (char*)d_ws;
    }
    short* Eh  = (short*)small;
    float* e2  = (float*)(Eh + (size_t)Kc * D);
    float* x2  = e2 + Kc;
    int*  cand = (int*)(x2 + N);

    conv_perm<<<N / 16, 256, 0, stream>>>(x, Xh, x2);
    conv_perm<<<Kc / 16, 256, 0, stream>>>(cb, Eh, e2);
    vq_gemm<<<(N / 32) * 2, 256, 0, stream>>>(Xh, Eh, e2, cand);
    vq_decide<<<N / 4, 256, 0, stream>>>(x, cb, cand, x2, e2, outq, outi);
}

// Round 6
// 71.474 us; speedup vs baseline: 1.7937x; 1.1575x over previous
//
#include <hip/hip_runtime.h>

#define D 256

typedef __attribute__((ext_vector_type(8))) _Float16 f16x8;
typedef __attribute__((ext_vector_type(8))) short    s16x8;
typedef __attribute__((ext_vector_type(4))) float    f4_t;
typedef unsigned long long ull;

// ---- fused: fp32 -> fp16 panel-permute + numpy-pairwise row sum-of-squares --
// panel: element (row,k) -> (row>>4)*4096 + (s*64 + chunk*16 + rr)*8 + e
//   s=k>>5, chunk=(k&31)>>3, rr=row&15, e=k&7. Wave frag read = base + lane*8.
__global__ __launch_bounds__(256) void conv_perm(const float* __restrict__ in,
    short* __restrict__ out, float* __restrict__ sq) {
    __shared__ float tile[16 * 264];
    const int t = threadIdx.x;
    const int p = blockIdx.x;
    const float* src = in + (size_t)p * 16 * 256;
#pragma unroll
    for (int it = 0; it < 4; ++it) {
        int idx = it * 256 + t;
        int row = idx >> 6, c4 = idx & 63;
        float4 v = *(const float4*)(src + row * 256 + c4 * 4);
        *(float4*)(tile + row * 264 + c4 * 4) = v;
    }
    __syncthreads();
    // rowsq: 16 threads/row, numpy pairwise order (8 strided accs + fixed tree)
    {
        int row = t >> 4, lane = t & 15;
        int b = lane >> 3, j = lane & 7;
        const float* q = tile + row * 264 + b * 128 + j;
        float r = 0.f;
        {
#pragma clang fp contract(off)
            for (int i = 0; i < 16; ++i) { float v = q[8 * i]; float s2 = v * v; r = r + s2; }
        }
        r += __shfl_xor(r, 1); r += __shfl_xor(r, 2);
        r += __shfl_xor(r, 4); r += __shfl_xor(r, 8);
        if (lane == 0) sq[p * 16 + row] = r;
    }
    // permute + fp16 convert (RTE)
#pragma unroll
    for (int jj = 0; jj < 2; ++jj) {
        int sl = jj * 256 + t;
        int s = sl >> 6, chunk = (sl >> 4) & 3, rr = sl & 15;
        const float* q = tile + rr * 264 + s * 32 + chunk * 8;
        s16x8 h8;
#pragma unroll
        for (int e = 0; e < 8; ++e) {
            _Float16 hv = (_Float16)q[e];
            h8[e] = (short)__builtin_bit_cast(unsigned short, hv);
        }
        *(s16x8*)(out + (size_t)p * 4096 + (size_t)sl * 8) = h8;
    }
}

// ---- main: tall-tile fp16 GEMM, B via LDS double-buffer (2-phase template) --
// Block: 128 rows x 512 codes (half h). 4 waves x 32 rows; A (32x256 fp16) in
// registers per wave; B panels (16 codes x 256 k = 8KB) staged to LDS once per
// block and shared by all 4 waves -> L2 B-traffic /4 vs register streaming.
// Top-2 per 256-code group kept via exact 64-bit keys (grp0 stashed at p=15).
__global__ __launch_bounds__(256, 2) void vq_gemm(
    const short* __restrict__ Xh, const short* __restrict__ Eh,
    const float* __restrict__ e2, int* __restrict__ cand) {
    __shared__ short Bs[8192];                  // 2 bufs x 4096 shorts (8KB)
    const int tid = threadIdx.x;
    const int l = tid & 63;
    const int w = tid >> 6;
    const int rb = blockIdx.x & 255;            // 256 row-blocks of 128 rows
    const int h  = blockIdx.x >> 8;             // code half (512 codes)
    const int R0 = rb * 128;
    const int pcBase = h * 32;                  // first of 32 code panels

    // A: wave's 32 rows x 256 k, 16 fragments in registers (loaded once)
    f16x8 aa[2][8];
#pragma unroll
    for (int m = 0; m < 2; ++m)
#pragma unroll
        for (int s = 0; s < 8; ++s)
            aa[m][s] = *(const f16x8*)(Xh +
                (size_t)((R0 >> 4) + w * 2 + m) * 4096 + s * 512 + l * 8);

    // prologue: stage panel 0 into buf 0 (each wave copies its 1KB x2 chunks)
    {
        const short* g = Eh + (size_t)pcBase * 4096 + w * 512 + l * 8;
        __builtin_amdgcn_global_load_lds(
            (const __attribute__((address_space(1))) void*)g,
            (__attribute__((address_space(3))) void*)(Bs + w * 512), 16, 0, 0);
        __builtin_amdgcn_global_load_lds(
            (const __attribute__((address_space(1))) void*)(g + 2048),
            (__attribute__((address_space(3))) void*)(Bs + 2048 + w * 512), 16, 0, 0);
    }
    __syncthreads();

    ull k1[2][4], k2[2][4];
#pragma unroll
    for (int m = 0; m < 2; ++m)
#pragma unroll
        for (int r = 0; r < 4; ++r) { k1[m][r] = ~0ull; k2[m][r] = ~0ull; }
    int cg0[2][4][2];                           // grp-0 candidate stash
#pragma unroll
    for (int m = 0; m < 2; ++m)
#pragma unroll
        for (int r = 0; r < 4; ++r) { cg0[m][r][0] = 0; cg0[m][r][1] = 0; }

#pragma unroll 1
    for (int p = 0; p < 32; ++p) {
        const int cur = p & 1;
        if (p < 31) {                           // stage next panel -> other buf
            const short* g = Eh + (size_t)(pcBase + p + 1) * 4096 + w * 512 + l * 8;
            short* dst = (short*)Bs + (cur ^ 1) * 4096 + w * 512;
            __builtin_amdgcn_global_load_lds(
                (const __attribute__((address_space(1))) void*)g,
                (__attribute__((address_space(3))) void*)dst, 16, 0, 0);
            __builtin_amdgcn_global_load_lds(
                (const __attribute__((address_space(1))) void*)(g + 2048),
                (__attribute__((address_space(3))) void*)(dst + 2048), 16, 0, 0);
        }
        const short* bp = (const short*)Bs + cur * 4096;
        f16x8 bb[8];
#pragma unroll
        for (int s = 0; s < 8; ++s)
            bb[s] = *(const f16x8*)(bp + s * 512 + l * 8);
        f4_t acc[2];
#pragma unroll
        for (int m = 0; m < 2; ++m) { f4_t z = {0.f,0.f,0.f,0.f}; acc[m] = z; }
#pragma unroll
        for (int s = 0; s < 8; ++s)
#pragma unroll
            for (int m = 0; m < 2; ++m)
                acc[m] = __builtin_amdgcn_mfma_f32_16x16x32_f16(
                    aa[m][s], bb[s], acc[m], 0, 0, 0);
        // fold into exact 64-bit keys: v = 0.5*e2 + 256 - xe (>0)
        int code = (pcBase + p) * 16 + (l & 15);
        float e2b = 0.5f * e2[code] + 256.0f;
#pragma unroll
        for (int m = 0; m < 2; ++m)
#pragma unroll
            for (int r = 0; r < 4; ++r) {
                float v = e2b - acc[m][r];
                ull key = ((ull)__builtin_bit_cast(unsigned int, v) << 32)
                        | (unsigned int)code;
                ull mx = k1[m][r] > key ? k1[m][r] : key;
                k1[m][r] = k1[m][r] < key ? k1[m][r] : key;
                k2[m][r] = k2[m][r] < mx ? k2[m][r] : mx;
            }
        if (p == 15) {                          // close group 0: reduce + stash
#pragma unroll
            for (int m = 0; m < 2; ++m)
#pragma unroll
                for (int r = 0; r < 4; ++r) {
                    ull a = k1[m][r], b = k2[m][r];
#pragma unroll
                    for (int msk = 1; msk < 16; msk <<= 1) {
                        ull oa = __shfl_xor(a, msk);
                        ull ob = __shfl_xor(b, msk);
                        ull hi_ = a > oa ? a : oa;
                        a = a < oa ? a : oa;
                        b = b < ob ? b : ob;
                        b = b < hi_ ? b : hi_;
                    }
                    cg0[m][r][0] = (int)(a & 1023ull);
                    cg0[m][r][1] = (int)(b & 1023ull);
                    k1[m][r] = ~0ull; k2[m][r] = ~0ull;
                }
        }
        __syncthreads();                        // drains stage loads (vmcnt 0)
    }

    // final reduce (group 1) and candidate writes
    if (true) {
        int q = l >> 4;
#pragma unroll
        for (int m = 0; m < 2; ++m)
#pragma unroll
            for (int r = 0; r < 4; ++r) {
                ull a = k1[m][r], b = k2[m][r];
#pragma unroll
                for (int msk = 1; msk < 16; msk <<= 1) {
                    ull oa = __shfl_xor(a, msk);
                    ull ob = __shfl_xor(b, msk);
                    ull hi_ = a > oa ? a : oa;
                    a = a < oa ? a : oa;
                    b = b < ob ? b : ob;
                    b = b < hi_ ? b : hi_;
                }
                if ((l & 15) == 0) {
                    int row = R0 + w * 32 + m * 16 + q * 4 + r;
                    int2 g0; g0.x = cg0[m][r][0]; g0.y = cg0[m][r][1];
                    int2 g1; g1.x = (int)(a & 1023ull); g1.y = (int)(b & 1023ull);
                    *(int2*)(cand + (size_t)row * 8 + h * 4 + 0) = g0;
                    *(int2*)(cand + (size_t)row * 8 + h * 4 + 2) = g1;
                }
            }
    }
}

// ---- exact fp32 recheck of 8 candidates (ref formula + tie-break) + gather --
// Coalesced: within each 8-lane candidate group, lane j reads float4 (i*8+j).
__global__ __launch_bounds__(256) void vq_decide(const float* __restrict__ x,
    const float* __restrict__ cb, const int* __restrict__ cand,
    const float* __restrict__ x2, const float* __restrict__ e2,
    float* __restrict__ outq, float* __restrict__ outi) {
    const int w = threadIdx.x >> 6, l = threadIdx.x & 63;
    const int row = blockIdx.x * 4 + w;
    const int o = l >> 3, j = l & 7;
    const int c = cand[(size_t)row * 8 + o];
    const float4* xr = (const float4*)(x + (size_t)row * D);
    const float4* er = (const float4*)(cb + (size_t)c * D);
    float xe = 0.f;
#pragma unroll
    for (int i = 0; i < 8; ++i) {
        float4 xv = xr[i * 8 + j], ev = er[i * 8 + j];
        xe = fmaf(xv.x, ev.x, xe); xe = fmaf(xv.y, ev.y, xe);
        xe = fmaf(xv.z, ev.z, xe); xe = fmaf(xv.w, ev.w, xe);
    }
    xe += __shfl_xor(xe, 1); xe += __shfl_xor(xe, 2); xe += __shfl_xor(xe, 4);
    float s0 = x2[row] + e2[c];                 // ref order: (x2 + e2) first
    float dist = s0 - 2.f * xe;                 // then - 2*xe
    float best = 3.4e38f; int bi = 0x7fffffff;
#pragma unroll
    for (int oq = 0; oq < 8; ++oq) {
        float dd = __shfl(dist, oq * 8);
        int   ii = __shfl(c,    oq * 8);
        if (dd < best || (dd == best && ii < bi)) { best = dd; bi = ii; }
    }
    float4 v = ((const float4*)(cb + (size_t)bi * D))[l];
    ((float4*)(outq + (size_t)row * D))[l] = v;
    if (l == 0) outi[row] = (float)bi;
}

extern "C" void kernel_launch(void* const* d_in, const int* in_sizes, int n_in,
                              void* d_out, int out_size, void* d_ws, size_t ws_size,
                              hipStream_t stream) {
    const float* x  = (const float*)d_in[0];
    const float* cb = (const float*)d_in[1];
    const int N  = in_sizes[0] / D;   // 32768
    const int Kc = in_sizes[1] / D;   // 1024

    float* outq = (float*)d_out;
    float* outi = outq + (size_t)N * D;

    const size_t needX = (size_t)N * D * 2;                       // fp16 X, 16 MB
    const size_t needS = (size_t)Kc * D * 2 + (size_t)Kc * 4
                       + (size_t)N * 4 + (size_t)N * 8 * 4;       // ~1.7 MB

    short* Xh; char* small;
    if (ws_size >= needX + needS) {
        Xh = (short*)d_ws;
        small = (char*)d_ws + needX;
    } else {
        // Xh lives in d_out[0,16MB). gemm reads it; vq_decide overwrites that
        // region with outq only after gemm completes (stream order). outi is
        // the last 128 KB of d_out -- no overlap.
        Xh = (short*)d_out;
        small = (char*)d_ws;
    }
    short* Eh  = (short*)small;
    float* e2  = (float*)(Eh + (size_t)Kc * D);
    float* x2  = e2 + Kc;
    int*  cand = (int*)(x2 + N);

    conv_perm<<<N / 16, 256, 0, stream>>>(x, Xh, x2);
    conv_perm<<<Kc / 16, 256, 0, stream>>>(cb, Eh, e2);
    vq_gemm<<<(N / 128) * 2, 256, 0, stream>>>(Xh, Eh, e2, cand);
    vq_decide<<<N / 4, 256, 0, stream>>>(x, cb, cand, x2, e2, outq, outi);
}

// Round 7
// 69.621 us; speedup vs baseline: 1.8414x; 1.0266x over previous
//
#include <hip/hip_runtime.h>

#define D 256

typedef __attribute__((ext_vector_type(8))) _Float16 f16x8;
typedef __attribute__((ext_vector_type(8))) short    s16x8;
typedef __attribute__((ext_vector_type(4))) float    f4_t;
typedef unsigned long long ull;

// ---- fused: fp32 -> fp16 panel-permute + numpy-pairwise row sum-of-squares --
__global__ __launch_bounds__(256) void conv_perm(const float* __restrict__ in,
    short* __restrict__ out, float* __restrict__ sq) {
    __shared__ float tile[16 * 264];
    const int t = threadIdx.x;
    const int p = blockIdx.x;
    const float* src = in + (size_t)p * 16 * 256;
#pragma unroll
    for (int it = 0; it < 4; ++it) {
        int idx = it * 256 + t;
        int row = idx >> 6, c4 = idx & 63;
        float4 v = *(const float4*)(src + row * 256 + c4 * 4);
        *(float4*)(tile + row * 264 + c4 * 4) = v;
    }
    __syncthreads();
    {
        int row = t >> 4, lane = t & 15;
        int b = lane >> 3, j = lane & 7;
        const float* q = tile + row * 264 + b * 128 + j;
        float r = 0.f;
        {
#pragma clang fp contract(off)
            for (int i = 0; i < 16; ++i) { float v = q[8 * i]; float s2 = v * v; r = r + s2; }
        }
        r += __shfl_xor(r, 1); r += __shfl_xor(r, 2);
        r += __shfl_xor(r, 4); r += __shfl_xor(r, 8);
        if (lane == 0) sq[p * 16 + row] = r;
    }
#pragma unroll
    for (int jj = 0; jj < 2; ++jj) {
        int sl = jj * 256 + t;
        int s = sl >> 6, chunk = (sl >> 4) & 3, rr = sl & 15;
        const float* q = tile + rr * 264 + s * 32 + chunk * 8;
        s16x8 h8;
#pragma unroll
        for (int e = 0; e < 8; ++e) {
            _Float16 hv = (_Float16)q[e];
            h8[e] = (short)__builtin_bit_cast(unsigned short, hv);
        }
        *(s16x8*)(out + (size_t)p * 4096 + (size_t)sl * 8) = h8;
    }
}

// ---- main: tall-tile fp16 GEMM, counted-vmcnt deep pipeline (T3+T4) --------
// Block: 128 rows x 512 codes (half h). 4 waves x 32 rows; A in registers.
// B: 16 superphases x 2 panels; 8 LDS bufs; stage issued 2 superphases ahead;
// s_waitcnt vmcnt(8) + raw s_barrier per superphase (never drain to 0 mid-loop).
// Safety: stage for sp s+2 (issued post-barrier_{s-1}) overwrites bufs last
// read in sp s-2, whose reads completed before any wave passed barrier_{s-1}.
__global__ __launch_bounds__(256, 2) void vq_gemm(
    const short* __restrict__ Xh, const short* __restrict__ Eh,
    const float* __restrict__ e2, int* __restrict__ cand) {
    __shared__ short Bs[8 * 4096];              // 8 panel bufs x 8KB = 64KB
    __shared__ float e2s[512];
    const int tid = threadIdx.x;
    const int l = tid & 63;
    const int w = tid >> 6;
    const int rb = blockIdx.x & 255;            // 256 row-blocks of 128 rows
    const int h  = blockIdx.x >> 8;             // code half (512 codes)
    const int R0 = rb * 128;
    const int pcBase = h * 32;                  // first of 32 code panels

#define STAGE(pp) do {                                                        \
    const short* g_ = Eh + (size_t)(pcBase + (pp)) * 4096 + w * 512 + l * 8;  \
    short* d_ = (short*)Bs + ((pp) & 7) * 4096 + w * 512;                     \
    __builtin_amdgcn_global_load_lds(                                         \
        (const __attribute__((address_space(1))) void*)g_,                    \
        (__attribute__((address_space(3))) void*)d_, 16, 0, 0);               \
    __builtin_amdgcn_global_load_lds(                                         \
        (const __attribute__((address_space(1))) void*)(g_ + 2048),           \
        (__attribute__((address_space(3))) void*)(d_ + 2048), 16, 0, 0);      \
} while (0)

    // A: wave's 32 rows x 256 k, 16 fragments in registers (loaded once)
    f16x8 aa[2][8];
#pragma unroll
    for (int m = 0; m < 2; ++m)
#pragma unroll
        for (int s = 0; s < 8; ++s)
            aa[m][s] = *(const f16x8*)(Xh +
                (size_t)((R0 >> 4) + w * 2 + m) * 4096 + s * 512 + l * 8);

    // e2 -> LDS, pre-biased (keeps main loop free of global loads -> vmcnt pure)
    e2s[tid]       = 0.5f * e2[h * 512 + tid]       + 256.0f;
    e2s[tid + 256] = 0.5f * e2[h * 512 + tid + 256] + 256.0f;

    STAGE(0); STAGE(1); STAGE(2); STAGE(3);     // sp0 + sp1 panels
    __syncthreads();                            // one-time full drain

    ull k1[2][4], k2[2][4];
#pragma unroll
    for (int m = 0; m < 2; ++m)
#pragma unroll
        for (int r = 0; r < 4; ++r) { k1[m][r] = ~0ull; k2[m][r] = ~0ull; }
    int cg0[2][4][2];
#pragma unroll
    for (int m = 0; m < 2; ++m)
#pragma unroll
        for (int r = 0; r < 4; ++r) { cg0[m][r][0] = 0; cg0[m][r][1] = 0; }

#define SPBODY(S)                                                             \
    __builtin_amdgcn_s_barrier();                                             \
    asm volatile("" ::: "memory");                                            \
    _Pragma("unroll")                                                         \
    for (int hp = 0; hp < 2; ++hp) {                                          \
        const int p = 2 * (S) + hp;                                           \
        const short* bp = (const short*)Bs + (p & 7) * 4096;                  \
        f16x8 bb[8];                                                          \
        _Pragma("unroll")                                                     \
        for (int k = 0; k < 8; ++k)                                           \
            bb[k] = *(const f16x8*)(bp + k * 512 + l * 8);                    \
        f4_t acc[2];                                                          \
        _Pragma("unroll")                                                     \
        for (int m = 0; m < 2; ++m) { f4_t z = {0.f,0.f,0.f,0.f}; acc[m] = z; } \
        _Pragma("unroll")                                                     \
        for (int k = 0; k < 8; ++k)                                           \
            _Pragma("unroll")                                                 \
            for (int m = 0; m < 2; ++m)                                       \
                acc[m] = __builtin_amdgcn_mfma_f32_16x16x32_f16(              \
                    aa[m][k], bb[k], acc[m], 0, 0, 0);                        \
        const int code = h * 512 + p * 16 + (l & 15);                         \
        const float e2b = e2s[p * 16 + (l & 15)];                             \
        _Pragma("unroll")                                                     \
        for (int m = 0; m < 2; ++m)                                           \
            _Pragma("unroll")                                                 \
            for (int r = 0; r < 4; ++r) {                                     \
                float v = e2b - acc[m][r];                                    \
                ull key = ((ull)__builtin_bit_cast(unsigned int, v) << 32)    \
                        | (unsigned int)code;                                 \
                ull mx = k1[m][r] > key ? k1[m][r] : key;                     \
                k1[m][r] = k1[m][r] < key ? k1[m][r] : key;                   \
                k2[m][r] = k2[m][r] < mx ? k2[m][r] : mx;                     \
            }                                                                 \
        if (p == 15) {                                                        \
            _Pragma("unroll")                                                 \
            for (int m = 0; m < 2; ++m)                                       \
                _Pragma("unroll")                                             \
                for (int r = 0; r < 4; ++r) {                                 \
                    ull a = k1[m][r], b = k2[m][r];                           \
                    _Pragma("unroll")                                         \
                    for (int msk = 1; msk < 16; msk <<= 1) {                  \
                        ull oa = __shfl_xor(a, msk);                          \
                        ull ob = __shfl_xor(b, msk);                          \
                        ull hi_ = a > oa ? a : oa;                            \
                        a = a < oa ? a : oa;                                  \
                        b = b < ob ? b : ob;                                  \
                        b = b < hi_ ? b : hi_;                                \
                    }                                                         \
                    cg0[m][r][0] = (int)(a & 1023ull);                        \
                    cg0[m][r][1] = (int)(b & 1023ull);                        \
                    k1[m][r] = ~0ull; k2[m][r] = ~0ull;                       \
                }                                                             \
        }                                                                     \
    }

#pragma unroll 1
    for (int s = 0; s < 14; ++s) {              // steady state: stage 2 sp ahead
        STAGE(2 * s + 4); STAGE(2 * s + 5);
        asm volatile("s_waitcnt vmcnt(8)" ::: "memory");
        SPBODY(s)
    }
    {                                           // sp14: nothing left to stage
        asm volatile("s_waitcnt vmcnt(4)" ::: "memory");
        SPBODY(14)
    }
    {                                           // sp15: drain
        asm volatile("s_waitcnt vmcnt(0)" ::: "memory");
        SPBODY(15)
    }

    // group-1 reduce and candidate writes
    {
        int q = l >> 4;
#pragma unroll
        for (int m = 0; m < 2; ++m)
#pragma unroll
            for (int r = 0; r < 4; ++r) {
                ull a = k1[m][r], b = k2[m][r];
#pragma unroll
                for (int msk = 1; msk < 16; msk <<= 1) {
                    ull oa = __shfl_xor(a, msk);
                    ull ob = __shfl_xor(b, msk);
                    ull hi_ = a > oa ? a : oa;
                    a = a < oa ? a : oa;
                    b = b < ob ? b : ob;
                    b = b < hi_ ? b : hi_;
                }
                if ((l & 15) == 0) {
                    int row = R0 + w * 32 + m * 16 + q * 4 + r;
                    int2 g0; g0.x = cg0[m][r][0]; g0.y = cg0[m][r][1];
                    int2 g1; g1.x = (int)(a & 1023ull); g1.y = (int)(b & 1023ull);
                    *(int2*)(cand + (size_t)row * 8 + h * 4 + 0) = g0;
                    *(int2*)(cand + (size_t)row * 8 + h * 4 + 2) = g1;
                }
            }
    }
#undef SPBODY
#undef STAGE
}

// ---- exact fp32 recheck of 8 candidates (ref formula + tie-break) + gather --
__global__ __launch_bounds__(256) void vq_decide(const float* __restrict__ x,
    const float* __restrict__ cb, const int* __restrict__ cand,
    const float* __restrict__ x2, const float* __restrict__ e2,
    float* __restrict__ outq, float* __restrict__ outi) {
    const int w = threadIdx.x >> 6, l = threadIdx.x & 63;
    const int row = blockIdx.x * 4 + w;
    const int o = l >> 3, j = l & 7;
    const int c = cand[(size_t)row * 8 + o];
    const float4* xr = (const float4*)(x + (size_t)row * D);
    const float4* er = (const float4*)(cb + (size_t)c * D);
    float xe = 0.f;
#pragma unroll
    for (int i = 0; i < 8; ++i) {
        float4 xv = xr[i * 8 + j], ev = er[i * 8 + j];
        xe = fmaf(xv.x, ev.x, xe); xe = fmaf(xv.y, ev.y, xe);
        xe = fmaf(xv.z, ev.z, xe); xe = fmaf(xv.w, ev.w, xe);
    }
    xe += __shfl_xor(xe, 1); xe += __shfl_xor(xe, 2); xe += __shfl_xor(xe, 4);
    float s0 = x2[row] + e2[c];                 // ref order: (x2 + e2) first
    float dist = s0 - 2.f * xe;                 // then - 2*xe
    float best = 3.4e38f; int bi = 0x7fffffff;
#pragma unroll
    for (int oq = 0; oq < 8; ++oq) {
        float dd = __shfl(dist, oq * 8);
        int   ii = __shfl(c,    oq * 8);
        if (dd < best || (dd == best && ii < bi)) { best = dd; bi = ii; }
    }
    float4 v = ((const float4*)(cb + (size_t)bi * D))[l];
    ((float4*)(outq + (size_t)row * D))[l] = v;
    if (l == 0) outi[row] = (float)bi;
}

extern "C" void kernel_launch(void* const* d_in, const int* in_sizes, int n_in,
                              void* d_out, int out_size, void* d_ws, size_t ws_size,
                              hipStream_t stream) {
    const float* x  = (const float*)d_in[0];
    const float* cb = (const float*)d_in[1];
    const int N  = in_sizes[0] / D;   // 32768
    const int Kc = in_sizes[1] / D;   // 1024

    float* outq = (float*)d_out;
    float* outi = outq + (size_t)N * D;

    const size_t needX = (size_t)N * D * 2;                       // fp16 X, 16 MB
    const size_t needS = (size_t)Kc * D * 2 + (size_t)Kc * 4
                       + (size_t)N * 4 + (size_t)N * 8 * 4;       // ~1.7 MB

    short* Xh; char* small;
    if (ws_size >= needX + needS) {
        Xh = (short*)d_ws;
        small = (char*)d_ws + needX;
    } else {
        // Xh lives in d_out[0,16MB). gemm reads it; vq_decide overwrites that
        // region with outq only after gemm completes (stream order). outi is
        // the last 128 KB of d_out -- no overlap.
        Xh = (short*)d_out;
        small = (char*)d_ws;
    }
    short* Eh  = (short*)small;
    float* e2  = (float*)(Eh + (size_t)Kc * D);
    float* x2  = e2 + Kc;
    int*  cand = (int*)(x2 + N);

    conv_perm<<<N / 16, 256, 0, stream>>>(x, Xh, x2);
    conv_perm<<<Kc / 16, 256, 0, stream>>>(cb, Eh, e2);
    vq_gemm<<<(N / 128) * 2, 256, 0, stream>>>(Xh, Eh, e2, cand);
    vq_decide<<<N / 4, 256, 0, stream>>>(x, cb, cand, x2, e2, outq, outi);
}

// Round 8
// 65.627 us; speedup vs baseline: 1.9535x; 1.0609x over previous
//
#include <hip/hip_runtime.h>

#define D 256

typedef __attribute__((ext_vector_type(8))) _Float16 f16x8;
typedef __attribute__((ext_vector_type(8))) short    s16x8;
typedef __attribute__((ext_vector_type(4))) float    f4_t;

// ---- fused: fp32 -> fp16 panel-permute + numpy-pairwise row sum-of-squares --
__global__ __launch_bounds__(256) void conv_perm(const float* __restrict__ in,
    short* __restrict__ out, float* __restrict__ sq) {
    __shared__ float tile[16 * 264];
    const int t = threadIdx.x;
    const int p = blockIdx.x;
    const float* src = in + (size_t)p * 16 * 256;
#pragma unroll
    for (int it = 0; it < 4; ++it) {
        int idx = it * 256 + t;
        int row = idx >> 6, c4 = idx & 63;
        float4 v = *(const float4*)(src + row * 256 + c4 * 4);
        *(float4*)(tile + row * 264 + c4 * 4) = v;
    }
    __syncthreads();
    {
        int row = t >> 4, lane = t & 15;
        int b = lane >> 3, j = lane & 7;
        const float* q = tile + row * 264 + b * 128 + j;
        float r = 0.f;
        {
#pragma clang fp contract(off)
            for (int i = 0; i < 16; ++i) { float v = q[8 * i]; float s2 = v * v; r = r + s2; }
        }
        r += __shfl_xor(r, 1); r += __shfl_xor(r, 2);
        r += __shfl_xor(r, 4); r += __shfl_xor(r, 8);
        if (lane == 0) sq[p * 16 + row] = r;
    }
#pragma unroll
    for (int jj = 0; jj < 2; ++jj) {
        int sl = jj * 256 + t;
        int s = sl >> 6, chunk = (sl >> 4) & 3, rr = sl & 15;
        const float* q = tile + rr * 264 + s * 32 + chunk * 8;
        s16x8 h8;
#pragma unroll
        for (int e = 0; e < 8; ++e) {
            _Float16 hv = (_Float16)q[e];
            h8[e] = (short)__builtin_bit_cast(unsigned short, hv);
        }
        *(s16x8*)(out + (size_t)p * 4096 + (size_t)sl * 8) = h8;
    }
}

// ---- main: 128 rows x 256 codes (quarter) per block; 6-buf counted-vmcnt ----
// 4 waves x 32 rows, A in registers; 16 B panels (16 codes x 256k = 8KB each).
// Body s: STAGE(sp s+2); vmcnt(8); barrier; ds_read sp s; MFMA; fold; barrier.
// Pre-barrier vmcnt(8) => each wave's quarter of sp-s panels resident before
// the barrier; end barrier => reads of sp s done before body s+1 stages into
// those bufs (6-buf reuse distance). u32 keys: sign-flipped fp32 bits, low 10
// bits = code; top-2 per 256-code group (== block) + exact fp32 recheck later.
__global__ __launch_bounds__(256, 3) void vq_gemm(
    const short* __restrict__ Xh, const short* __restrict__ Eh,
    const float* __restrict__ e2, int* __restrict__ cand) {
    __shared__ short Bs[6 * 4096];              // 6 panel bufs x 8KB = 48KB
    __shared__ float e2s[256];
    const int tid = threadIdx.x;
    const int l = tid & 63;
    const int w = tid >> 6;
    const int rb = blockIdx.x & 255;            // 256 row-blocks of 128 rows
    const int q  = blockIdx.x >> 8;             // code quarter (256 codes)
    const int R0 = rb * 128;
    const int pcBase = q * 16;                  // first of 16 code panels

#define STAGE(pp) do {                                                        \
    const short* g_ = Eh + (size_t)(pcBase + (pp)) * 4096 + w * 512 + l * 8;  \
    short* d_ = (short*)Bs + ((pp) % 6) * 4096 + w * 512;                     \
    __builtin_amdgcn_global_load_lds(                                         \
        (const __attribute__((address_space(1))) void*)g_,                    \
        (__attribute__((address_space(3))) void*)d_, 16, 0, 0);               \
    __builtin_amdgcn_global_load_lds(                                         \
        (const __attribute__((address_space(1))) void*)(g_ + 2048),           \
        (__attribute__((address_space(3))) void*)(d_ + 2048), 16, 0, 0);      \
} while (0)

    // A: wave's 32 rows x 256 k, 16 fragments in registers (loaded once)
    f16x8 aa[2][8];
#pragma unroll
    for (int m = 0; m < 2; ++m)
#pragma unroll
        for (int s = 0; s < 8; ++s)
            aa[m][s] = *(const f16x8*)(Xh +
                (size_t)((R0 >> 4) + w * 2 + m) * 4096 + s * 512 + l * 8);

    e2s[tid < 256 ? tid : 0] = 0.5f * e2[q * 256 + (tid < 256 ? tid : 0)];

    STAGE(0); STAGE(1); STAGE(2); STAGE(3);     // sp0 + sp1 panels
    __syncthreads();                            // one-time full drain

    unsigned int k1[2][4], k2[2][4];
#pragma unroll
    for (int m = 0; m < 2; ++m)
#pragma unroll
        for (int r = 0; r < 4; ++r) { k1[m][r] = 0xFFFFFFFFu; k2[m][r] = 0xFFFFFFFFu; }

#define SPBODY(S)                                                             \
    __builtin_amdgcn_s_barrier();                                             \
    asm volatile("" ::: "memory");                                            \
    _Pragma("unroll")                                                         \
    for (int hp = 0; hp < 2; ++hp) {                                          \
        const int p = 2 * (S) + hp;                                           \
        const short* bp = (const short*)Bs + (p % 6) * 4096;                  \
        f4_t acc[2][2];                                                       \
        _Pragma("unroll")                                                     \
        for (int m = 0; m < 2; ++m) {                                         \
            f4_t z = {0.f,0.f,0.f,0.f}; acc[m][0] = z; acc[m][1] = z;         \
        }                                                                     \
        {                                                                     \
            f16x8 bb[4];                                                      \
            _Pragma("unroll")                                                 \
            for (int k = 0; k < 4; ++k)                                       \
                bb[k] = *(const f16x8*)(bp + k * 512 + l * 8);                \
            _Pragma("unroll")                                                 \
            for (int k = 0; k < 4; ++k)                                       \
                _Pragma("unroll")                                             \
                for (int m = 0; m < 2; ++m)                                   \
                    acc[m][0] = __builtin_amdgcn_mfma_f32_16x16x32_f16(       \
                        aa[m][k], bb[k], acc[m][0], 0, 0, 0);                 \
        }                                                                     \
        {                                                                     \
            f16x8 bb[4];                                                      \
            _Pragma("unroll")                                                 \
            for (int k = 0; k < 4; ++k)                                       \
                bb[k] = *(const f16x8*)(bp + (k + 4) * 512 + l * 8);          \
            _Pragma("unroll")                                                 \
            for (int k = 0; k < 4; ++k)                                       \
                _Pragma("unroll")                                             \
                for (int m = 0; m < 2; ++m)                                   \
                    acc[m][1] = __builtin_amdgcn_mfma_f32_16x16x32_f16(       \
                        aa[m][k + 4], bb[k], acc[m][1], 0, 0, 0);             \
        }                                                                     \
        const unsigned int code = (unsigned int)(q * 256 + p * 16 + (l & 15));\
        const float e2b = e2s[p * 16 + (l & 15)];                             \
        _Pragma("unroll")                                                     \
        for (int m = 0; m < 2; ++m)                                           \
            _Pragma("unroll")                                                 \
            for (int r = 0; r < 4; ++r) {                                     \
                float v = e2b - (acc[m][0][r] + acc[m][1][r]);                \
                unsigned int u = __builtin_bit_cast(unsigned int, v);         \
                unsigned int f = u ^ ((unsigned int)((int)u >> 31)            \
                                     | 0x80000000u);                          \
                unsigned int key = (f & 0xFFFFFC00u) | code;                  \
                unsigned int mx = k1[m][r] > key ? k1[m][r] : key;            \
                k1[m][r] = k1[m][r] < key ? k1[m][r] : key;                   \
                k2[m][r] = k2[m][r] < mx ? k2[m][r] : mx;                     \
            }                                                                 \
    }                                                                         \
    __builtin_amdgcn_s_barrier();                                             \
    asm volatile("" ::: "memory");

#pragma unroll 1
    for (int s = 0; s < 6; ++s) {               // steady state: stage 2 sp ahead
        STAGE(2 * s + 4); STAGE(2 * s + 5);
        asm volatile("s_waitcnt vmcnt(8)" ::: "memory");
        SPBODY(s)
    }
    {
        asm volatile("s_waitcnt vmcnt(4)" ::: "memory");
        SPBODY(6)
    }
    {
        asm volatile("s_waitcnt vmcnt(0)" ::: "memory");
        SPBODY(7)
    }

    // top-2 reduce across the 16 lanes sharing each row; write candidates
    {
        int q4 = l >> 4;
#pragma unroll
        for (int m = 0; m < 2; ++m)
#pragma unroll
            for (int r = 0; r < 4; ++r) {
                unsigned int a = k1[m][r], b = k2[m][r];
#pragma unroll
                for (int msk = 1; msk < 16; msk <<= 1) {
                    unsigned int oa = __shfl_xor(a, msk);
                    unsigned int ob = __shfl_xor(b, msk);
                    unsigned int hi_ = a > oa ? a : oa;
                    a = a < oa ? a : oa;
                    b = b < ob ? b : ob;
                    b = b < hi_ ? b : hi_;
                }
                if ((l & 15) == 0) {
                    int row = R0 + w * 32 + m * 16 + q4 * 4 + r;
                    int2 o; o.x = (int)(a & 1023u); o.y = (int)(b & 1023u);
                    *(int2*)(cand + (size_t)row * 8 + q * 2) = o;
                }
            }
    }
#undef SPBODY
#undef STAGE
}

// ---- exact fp32 recheck of 8 candidates (ref formula + tie-break) + gather --
__global__ __launch_bounds__(256) void vq_decide(const float* __restrict__ x,
    const float* __restrict__ cb, const int* __restrict__ cand,
    const float* __restrict__ x2, const float* __restrict__ e2,
    float* __restrict__ outq, float* __restrict__ outi) {
    const int w = threadIdx.x >> 6, l = threadIdx.x & 63;
    const int row = blockIdx.x * 4 + w;
    const int o = l >> 3, j = l & 7;
    const int c = cand[(size_t)row * 8 + o];
    const float4* xr = (const float4*)(x + (size_t)row * D);
    const float4* er = (const float4*)(cb + (size_t)c * D);
    float xe = 0.f;
#pragma unroll
    for (int i = 0; i < 8; ++i) {
        float4 xv = xr[i * 8 + j], ev = er[i * 8 + j];
        xe = fmaf(xv.x, ev.x, xe); xe = fmaf(xv.y, ev.y, xe);
        xe = fmaf(xv.z, ev.z, xe); xe = fmaf(xv.w, ev.w, xe);
    }
    xe += __shfl_xor(xe, 1); xe += __shfl_xor(xe, 2); xe += __shfl_xor(xe, 4);
    float s0 = x2[row] + e2[c];                 // ref order: (x2 + e2) first
    float dist = s0 - 2.f * xe;                 // then - 2*xe
    float best = 3.4e38f; int bi = 0x7fffffff;
#pragma unroll
    for (int oq = 0; oq < 8; ++oq) {
        float dd = __shfl(dist, oq * 8);
        int   ii = __shfl(c,    oq * 8);
        if (dd < best || (dd == best && ii < bi)) { best = dd; bi = ii; }
    }
    float4 v = ((const float4*)(cb + (size_t)bi * D))[l];
    ((float4*)(outq + (size_t)row * D))[l] = v;
    if (l == 0) outi[row] = (float)bi;
}

extern "C" void kernel_launch(void* const* d_in, const int* in_sizes, int n_in,
                              void* d_out, int out_size, void* d_ws, size_t ws_size,
                              hipStream_t stream) {
    const float* x  = (const float*)d_in[0];
    const float* cb = (const float*)d_in[1];
    const int N  = in_sizes[0] / D;   // 32768
    const int Kc = in_sizes[1] / D;   // 1024

    float* outq = (float*)d_out;
    float* outi = outq + (size_t)N * D;

    const size_t needX = (size_t)N * D * 2;                       // fp16 X, 16 MB
    const size_t needS = (size_t)Kc * D * 2 + (size_t)Kc * 4
                       + (size_t)N * 4 + (size_t)N * 8 * 4;       // ~1.7 MB

    short* Xh; char* small;
    if (ws_size >= needX + needS) {
        Xh = (short*)d_ws;
        small = (char*)d_ws + needX;
    } else {
        // Xh lives in d_out[0,16MB). gemm reads it; vq_decide overwrites that
        // region with outq only after gemm completes (stream order). outi is
        // the last 128 KB of d_out -- no overlap.
        Xh = (short*)d_out;
        small = (char*)d_ws;
    }
    short* Eh  = (short*)small;
    float* e2  = (float*)(Eh + (size_t)Kc * D);
    float* x2  = e2 + Kc;
    int*  cand = (int*)(x2 + N);

    conv_perm<<<N / 16, 256, 0, stream>>>(x, Xh, x2);
    conv_perm<<<Kc / 16, 256, 0, stream>>>(cb, Eh, e2);
    vq_gemm<<<(N / 128) * 4, 256, 0, stream>>>(Xh, Eh, e2, cand);
    vq_decide<<<N / 4, 256, 0, stream>>>(x, cb, cand, x2, e2, outq, outi);
}

// Round 9
// 64.832 us; speedup vs baseline: 1.9775x; 1.0123x over previous
//
#include <hip/hip_runtime.h>

#define D 256

typedef __attribute__((ext_vector_type(8))) _Float16 f16x8;
typedef __attribute__((ext_vector_type(8))) short    s16x8;
typedef __attribute__((ext_vector_type(4))) float    f4_t;

// ---- merged conv: fp32 -> fp16 panel-permute + numpy-pairwise rowsq --------
// blocks [0,nx): x -> xh,x2 ; blocks [nx, nx+K/16): cb -> eh,e2
__global__ __launch_bounds__(256) void conv_all(
    const float* __restrict__ x, short* __restrict__ xh, float* __restrict__ x2,
    const float* __restrict__ cb, short* __restrict__ eh, float* __restrict__ e2,
    int nx) {
    __shared__ float tile[16 * 264];
    const int t = threadIdx.x;
    const int bid = blockIdx.x;
    const float* in; short* out; float* sq; int p;
    if (bid < nx) { in = x;  out = xh; sq = x2; p = bid; }
    else          { in = cb; out = eh; sq = e2; p = bid - nx; }
    const float* src = in + (size_t)p * 16 * 256;
#pragma unroll
    for (int it = 0; it < 4; ++it) {
        int idx = it * 256 + t;
        int row = idx >> 6, c4 = idx & 63;
        float4 v = *(const float4*)(src + row * 256 + c4 * 4);
        *(float4*)(tile + row * 264 + c4 * 4) = v;
    }
    __syncthreads();
    {   // rowsq: 16 threads/row, numpy pairwise order
        int row = t >> 4, lane = t & 15;
        int b = lane >> 3, j = lane & 7;
        const float* q = tile + row * 264 + b * 128 + j;
        float r = 0.f;
        {
#pragma clang fp contract(off)
            for (int i = 0; i < 16; ++i) { float v = q[8 * i]; float s2 = v * v; r = r + s2; }
        }
        r += __shfl_xor(r, 1); r += __shfl_xor(r, 2);
        r += __shfl_xor(r, 4); r += __shfl_xor(r, 8);
        if (lane == 0) sq[p * 16 + row] = r;
    }
#pragma unroll
    for (int jj = 0; jj < 2; ++jj) {
        int sl = jj * 256 + t;
        int s = sl >> 6, chunk = (sl >> 4) & 3, rr = sl & 15;
        const float* q = tile + rr * 264 + s * 32 + chunk * 8;
        s16x8 h8;
#pragma unroll
        for (int e = 0; e < 8; ++e) {
            _Float16 hv = (_Float16)q[e];
            h8[e] = (short)__builtin_bit_cast(unsigned short, hv);
        }
        *(s16x8*)(out + (size_t)p * 4096 + (size_t)sl * 8) = h8;
    }
}

// ---- FUSED: gemm + top-2/quarter (LDS cand) + exact recheck + gather -------
// 256 blocks x 1024 thr (16 waves = 8 row-grps x 2 halves). BM=128, BN=1024.
// Per half: 32 panels, 6 LDS bufs, stage-2-sp-ahead, vmcnt(4)/(2)/(0) (R8
// schedule). Quarter top-2 (u32 keys, exact recheck later) stashed to LDS.
// Epilogue: per row exact fp32 dist over 8 cands (ref formula + tie-break),
// gather write. WAR ledger as R8: stage into buf (2s+4)%6 = buf read in sp
// s-1, whose reads finished before s-1's end barrier, which precedes STAGE.
__global__ __launch_bounds__(1024, 4) void vq_fused(
    const short* __restrict__ Xh, const short* __restrict__ Eh,
    const float* __restrict__ e2b_, const float* __restrict__ x2g,
    const float* __restrict__ x, const float* __restrict__ cb,
    float* __restrict__ outq, float* __restrict__ outi) {
    __shared__ short Bs[2 * 6 * 4096];          // 96 KB: [half][6 bufs][8KB]
    __shared__ float e2s[1024];                 // biased 0.5*e2+256
    __shared__ int   candL[128][8];             // top-2 x 4 quarters per row
    const int tid = threadIdx.x;
    const int l  = tid & 63;
    const int w  = tid >> 6;                    // 0..15
    const int hh = w & 1;                       // code half
    const int mg = w >> 1;                      // row group 0..7
    const int R0 = blockIdx.x * 128;

#define STAGE(pp) do {                                                        \
    const int hs_ = tid >> 9, li_ = tid & 511;                                \
    const short* g_ = Eh + (size_t)(hs_ * 32 + (pp)) * 4096 + li_ * 8;        \
    short* d_ = (short*)Bs + hs_ * 24576 + ((pp) % 6) * 4096 + li_ * 8;       \
    __builtin_amdgcn_global_load_lds(                                         \
        (const __attribute__((address_space(1))) void*)g_,                    \
        (__attribute__((address_space(3))) void*)d_, 16, 0, 0);               \
} while (0)

    // A: wave's 16 rows x 256 k in registers (loaded once)
    f16x8 aa[8];
#pragma unroll
    for (int s = 0; s < 8; ++s)
        aa[s] = *(const f16x8*)(Xh +
            (size_t)((R0 >> 4) + mg) * 4096 + s * 512 + l * 8);

    e2s[tid] = 0.5f * e2b_[tid] + 256.0f;

    STAGE(0); STAGE(1); STAGE(2); STAGE(3);
    __syncthreads();                            // one-time full drain

    unsigned int k1[4], k2[4];
#pragma unroll
    for (int r = 0; r < 4; ++r) { k1[r] = 0xFFFFFFFFu; k2[r] = 0xFFFFFFFFu; }

#define SPBODY(S)                                                             \
    __builtin_amdgcn_s_barrier();                                             \
    asm volatile("" ::: "memory");                                            \
    _Pragma("unroll")                                                         \
    for (int hp = 0; hp < 2; ++hp) {                                          \
        const int p = 2 * (S) + hp;                                           \
        const short* bp = (const short*)Bs + hh * 24576 + (p % 6) * 4096;     \
        f4_t acc0 = {0.f,0.f,0.f,0.f}, acc1 = {0.f,0.f,0.f,0.f};              \
        {                                                                     \
            f16x8 bb[4];                                                      \
            _Pragma("unroll")                                                 \
            for (int k = 0; k < 4; ++k)                                       \
                bb[k] = *(const f16x8*)(bp + k * 512 + l * 8);                \
            _Pragma("unroll")                                                 \
            for (int k = 0; k < 4; ++k)                                       \
                acc0 = __builtin_amdgcn_mfma_f32_16x16x32_f16(                \
                    aa[k], bb[k], acc0, 0, 0, 0);                             \
        }                                                                     \
        {                                                                     \
            f16x8 bb[4];                                                      \
            _Pragma("unroll")                                                 \
            for (int k = 0; k < 4; ++k)                                       \
                bb[k] = *(const f16x8*)(bp + (k + 4) * 512 + l * 8);          \
            _Pragma("unroll")                                                 \
            for (int k = 0; k < 4; ++k)                                       \
                acc1 = __builtin_amdgcn_mfma_f32_16x16x32_f16(                \
                    aa[k + 4], bb[k], acc1, 0, 0, 0);                         \
        }                                                                     \
        const unsigned int code = (unsigned int)(hh * 512 + p * 16 + (l & 15));\
        const float e2v = e2s[hh * 512 + p * 16 + (l & 15)];                  \
        _Pragma("unroll")                                                     \
        for (int r = 0; r < 4; ++r) {                                         \
            float v = e2v - (acc0[r] + acc1[r]);                              \
            unsigned int u = __builtin_bit_cast(unsigned int, v);             \
            unsigned int f = u ^ ((unsigned int)((int)u >> 31) | 0x80000000u);\
            unsigned int key = (f & 0xFFFFFC00u) | code;                      \
            unsigned int mx = k1[r] > key ? k1[r] : key;                      \
            k1[r] = k1[r] < key ? k1[r] : key;                                \
            k2[r] = k2[r] < mx ? k2[r] : mx;                                  \
        }                                                                     \
        if (p == 15 || p == 31) {               /* close quarter: stash */    \
            const int q_ = hh * 2 + (p >> 4);                                 \
            _Pragma("unroll")                                                 \
            for (int r = 0; r < 4; ++r) {                                     \
                unsigned int a = k1[r], b = k2[r];                            \
                _Pragma("unroll")                                             \
                for (int msk = 1; msk < 16; msk <<= 1) {                      \
                    unsigned int oa = __shfl_xor(a, msk);                     \
                    unsigned int ob = __shfl_xor(b, msk);                     \
                    unsigned int hi_ = a > oa ? a : oa;                       \
                    a = a < oa ? a : oa;                                      \
                    b = b < ob ? b : ob;                                      \
                    b = b < hi_ ? b : hi_;                                    \
                }                                                             \
                if ((l & 15) == 0) {                                          \
                    int rl_ = mg * 16 + (l >> 4) * 4 + r;                     \
                    candL[rl_][2 * q_ + 0] = (int)(a & 1023u);                \
                    candL[rl_][2 * q_ + 1] = (int)(b & 1023u);                \
                }                                                             \
                k1[r] = 0xFFFFFFFFu; k2[r] = 0xFFFFFFFFu;                     \
            }                                                                 \
        }                                                                     \
    }                                                                         \
    __builtin_amdgcn_s_barrier();                                             \
    asm volatile("" ::: "memory");

#pragma unroll 1
    for (int s = 0; s < 14; ++s) {
        STAGE(2 * s + 4); STAGE(2 * s + 5);
        asm volatile("s_waitcnt vmcnt(4)" ::: "memory");
        SPBODY(s)
    }
    {
        asm volatile("s_waitcnt vmcnt(2)" ::: "memory");
        SPBODY(14)
    }
    {
        asm volatile("s_waitcnt vmcnt(0)" ::: "memory");
        SPBODY(15)
    }
#undef SPBODY
#undef STAGE

    __syncthreads();                            // candL visibility

    // ---- fused decide + gather: 16 waves x 8 rows each ----
#pragma unroll 1
    for (int rr = 0; rr < 8; ++rr) {
        const int rl = w * 8 + rr;
        const int row = R0 + rl;
        const int o = l >> 3, j = l & 7;
        const int c = candL[rl][o];
        const float4* xr = (const float4*)(x + (size_t)row * D);
        const float4* er = (const float4*)(cb + (size_t)c * D);
        float xe = 0.f;
#pragma unroll
        for (int i = 0; i < 8; ++i) {
            float4 xv = xr[i * 8 + j], ev = er[i * 8 + j];
            xe = fmaf(xv.x, ev.x, xe); xe = fmaf(xv.y, ev.y, xe);
            xe = fmaf(xv.z, ev.z, xe); xe = fmaf(xv.w, ev.w, xe);
        }
        xe += __shfl_xor(xe, 1); xe += __shfl_xor(xe, 2); xe += __shfl_xor(xe, 4);
        float s0 = x2g[row] + e2b_[c];          // ref order: (x2 + e2) first
        float dist = s0 - 2.f * xe;             // then - 2*xe
        float best = 3.4e38f; int bi = 0x7fffffff;
#pragma unroll
        for (int oq = 0; oq < 8; ++oq) {
            float dd = __shfl(dist, oq * 8);
            int   ii = __shfl(c,    oq * 8);
            if (dd < best || (dd == best && ii < bi)) { best = dd; bi = ii; }
        }
        float4 v = ((const float4*)(cb + (size_t)bi * D))[l];
        ((float4*)(outq + (size_t)row * D))[l] = v;
        if (l == 0) outi[row] = (float)bi;
    }
}

// ================= fallback path (ws too small): R8 pipeline ================
__global__ __launch_bounds__(256, 3) void vq_gemm(
    const short* __restrict__ Xh, const short* __restrict__ Eh,
    const float* __restrict__ e2, int* __restrict__ cand) {
    __shared__ short Bs[6 * 4096];
    __shared__ float e2s[256];
    const int tid = threadIdx.x;
    const int l = tid & 63;
    const int w = tid >> 6;
    const int rb = blockIdx.x & 255;
    const int q  = blockIdx.x >> 8;
    const int R0 = rb * 128;
    const int pcBase = q * 16;

#define STAGE(pp) do {                                                        \
    const short* g_ = Eh + (size_t)(pcBase + (pp)) * 4096 + w * 512 + l * 8;  \
    short* d_ = (short*)Bs + ((pp) % 6) * 4096 + w * 512;                     \
    __builtin_amdgcn_global_load_lds(                                         \
        (const __attribute__((address_space(1))) void*)g_,                    \
        (__attribute__((address_space(3))) void*)d_, 16, 0, 0);               \
    __builtin_amdgcn_global_load_lds(                                         \
        (const __attribute__((address_space(1))) void*)(g_ + 2048),           \
        (__attribute__((address_space(3))) void*)(d_ + 2048), 16, 0, 0);      \
} while (0)

    f16x8 aa[2][8];
#pragma unroll
    for (int m = 0; m < 2; ++m)
#pragma unroll
        for (int s = 0; s < 8; ++s)
            aa[m][s] = *(const f16x8*)(Xh +
                (size_t)((R0 >> 4) + w * 2 + m) * 4096 + s * 512 + l * 8);

    e2s[tid < 256 ? tid : 0] = 0.5f * e2[q * 256 + (tid < 256 ? tid : 0)];

    STAGE(0); STAGE(1); STAGE(2); STAGE(3);
    __syncthreads();

    unsigned int k1[2][4], k2[2][4];
#pragma unroll
    for (int m = 0; m < 2; ++m)
#pragma unroll
        for (int r = 0; r < 4; ++r) { k1[m][r] = 0xFFFFFFFFu; k2[m][r] = 0xFFFFFFFFu; }

#define SPBODY(S)                                                             \
    __builtin_amdgcn_s_barrier();                                             \
    asm volatile("" ::: "memory");                                            \
    _Pragma("unroll")                                                         \
    for (int hp = 0; hp < 2; ++hp) {                                          \
        const int p = 2 * (S) + hp;                                           \
        const short* bp = (const short*)Bs + (p % 6) * 4096;                  \
        f4_t acc[2][2];                                                       \
        _Pragma("unroll")                                                     \
        for (int m = 0; m < 2; ++m) {                                         \
            f4_t z = {0.f,0.f,0.f,0.f}; acc[m][0] = z; acc[m][1] = z;         \
        }                                                                     \
        {                                                                     \
            f16x8 bb[4];                                                      \
            _Pragma("unroll")                                                 \
            for (int k = 0; k < 4; ++k)                                       \
                bb[k] = *(const f16x8*)(bp + k * 512 + l * 8);                \
            _Pragma("unroll")                                                 \
            for (int k = 0; k < 4; ++k)                                       \
                _Pragma("unroll")                                             \
                for (int m = 0; m < 2; ++m)                                   \
                    acc[m][0] = __builtin_amdgcn_mfma_f32_16x16x32_f16(       \
                        aa[m][k], bb[k], acc[m][0], 0, 0, 0);                 \
        }                                                                     \
        {                                                                     \
            f16x8 bb[4];                                                      \
            _Pragma("unroll")                                                 \
            for (int k = 0; k < 4; ++k)                                       \
                bb[k] = *(const f16x8*)(bp + (k + 4) * 512 + l * 8);          \
            _Pragma("unroll")                                                 \
            for (int k = 0; k < 4; ++k)                                       \
                _Pragma("unroll")                                             \
                for (int m = 0; m < 2; ++m)                                   \
                    acc[m][1] = __builtin_amdgcn_mfma_f32_16x16x32_f16(       \
                        aa[m][k + 4], bb[k], acc[m][1], 0, 0, 0);             \
        }                                                                     \
        const unsigned int code = (unsigned int)(q * 256 + p * 16 + (l & 15));\
        const float e2b = e2s[p * 16 + (l & 15)];                             \
        _Pragma("unroll")                                                     \
        for (int m = 0; m < 2; ++m)                                           \
            _Pragma("unroll")                                                 \
            for (int r = 0; r < 4; ++r) {                                     \
                float v = e2b - (acc[m][0][r] + acc[m][1][r]);                \
                unsigned int u = __builtin_bit_cast(unsigned int, v);         \
                unsigned int f = u ^ ((unsigned int)((int)u >> 31)            \
                                     | 0x80000000u);                          \
                unsigned int key = (f & 0xFFFFFC00u) | code;                  \
                unsigned int mx = k1[m][r] > key ? k1[m][r] : key;            \
                k1[m][r] = k1[m][r] < key ? k1[m][r] : key;                   \
                k2[m][r] = k2[m][r] < mx ? k2[m][r] : mx;                     \
            }                                                                 \
    }                                                                         \
    __builtin_amdgcn_s_barrier();                                             \
    asm volatile("" ::: "memory");

#pragma unroll 1
    for (int s = 0; s < 6; ++s) {
        STAGE(2 * s + 4); STAGE(2 * s + 5);
        asm volatile("s_waitcnt vmcnt(8)" ::: "memory");
        SPBODY(s)
    }
    {
        asm volatile("s_waitcnt vmcnt(4)" ::: "memory");
        SPBODY(6)
    }
    {
        asm volatile("s_waitcnt vmcnt(0)" ::: "memory");
        SPBODY(7)
    }
    {
        int q4 = l >> 4;
#pragma unroll
        for (int m = 0; m < 2; ++m)
#pragma unroll
            for (int r = 0; r < 4; ++r) {
                unsigned int a = k1[m][r], b = k2[m][r];
#pragma unroll
                for (int msk = 1; msk < 16; msk <<= 1) {
                    unsigned int oa = __shfl_xor(a, msk);
                    unsigned int ob = __shfl_xor(b, msk);
                    unsigned int hi_ = a > oa ? a : oa;
                    a = a < oa ? a : oa;
                    b = b < ob ? b : ob;
                    b = b < hi_ ? b : hi_;
                }
                if ((l & 15) == 0) {
                    int row = R0 + w * 32 + m * 16 + q4 * 4 + r;
                    int2 o; o.x = (int)(a & 1023u); o.y = (int)(b & 1023u);
                    *(int2*)(cand + (size_t)row * 8 + q * 2) = o;
                }
            }
    }
#undef SPBODY
#undef STAGE
}

__global__ __launch_bounds__(256) void vq_decide(const float* __restrict__ x,
    const float* __restrict__ cb, const int* __restrict__ cand,
    const float* __restrict__ x2, const float* __restrict__ e2,
    float* __restrict__ outq, float* __restrict__ outi) {
    const int w = threadIdx.x >> 6, l = threadIdx.x & 63;
    const int row = blockIdx.x * 4 + w;
    const int o = l >> 3, j = l & 7;
    const int c = cand[(size_t)row * 8 + o];
    const float4* xr = (const float4*)(x + (size_t)row * D);
    const float4* er = (const float4*)(cb + (size_t)c * D);
    float xe = 0.f;
#pragma unroll
    for (int i = 0; i < 8; ++i) {
        float4 xv = xr[i * 8 + j], ev = er[i * 8 + j];
        xe = fmaf(xv.x, ev.x, xe); xe = fmaf(xv.y, ev.y, xe);
        xe = fmaf(xv.z, ev.z, xe); xe = fmaf(xv.w, ev.w, xe);
    }
    xe += __shfl_xor(xe, 1); xe += __shfl_xor(xe, 2); xe += __shfl_xor(xe, 4);
    float s0 = x2[row] + e2[c];
    float dist = s0 - 2.f * xe;
    float best = 3.4e38f; int bi = 0x7fffffff;
#pragma unroll
    for (int oq = 0; oq < 8; ++oq) {
        float dd = __shfl(dist, oq * 8);
        int   ii = __shfl(c,    oq * 8);
        if (dd < best || (dd == best && ii < bi)) { best = dd; bi = ii; }
    }
    float4 v = ((const float4*)(cb + (size_t)bi * D))[l];
    ((float4*)(outq + (size_t)row * D))[l] = v;
    if (l == 0) outi[row] = (float)bi;
}

extern "C" void kernel_launch(void* const* d_in, const int* in_sizes, int n_in,
                              void* d_out, int out_size, void* d_ws, size_t ws_size,
                              hipStream_t stream) {
    const float* x  = (const float*)d_in[0];
    const float* cb = (const float*)d_in[1];
    const int N  = in_sizes[0] / D;   // 32768
    const int Kc = in_sizes[1] / D;   // 1024

    float* outq = (float*)d_out;
    float* outi = outq + (size_t)N * D;

    const size_t needX = (size_t)N * D * 2;                        // 16 MB
    const size_t needS = (size_t)Kc * D * 2 + (size_t)Kc * 4
                       + (size_t)N * 4 + (size_t)N * 8 * 4;        // ~1.7 MB

    if (ws_size >= needX + needS) {
        // ---------------- fused path: 2 launches ----------------
        short* Xh  = (short*)d_ws;
        short* Eh  = Xh + (size_t)N * D;
        float* e2  = (float*)(Eh + (size_t)Kc * D);
        float* x2  = e2 + Kc;
        conv_all<<<N / 16 + Kc / 16, 256, 0, stream>>>(x, Xh, x2, cb, Eh, e2, N / 16);
        vq_fused<<<N / 128, 1024, 0, stream>>>(Xh, Eh, e2, x2, x, cb, outq, outi);
    } else {
        // ---------------- fallback: R8 4-stage pipeline ----------------
        short* Xh  = (short*)d_out;   // overwritten by outq only after gemm
        char* small = (char*)d_ws;
        short* Eh  = (short*)small;
        float* e2  = (float*)(Eh + (size_t)Kc * D);
        float* x2  = e2 + Kc;
        int*  cand = (int*)(x2 + N);
        conv_all<<<N / 16 + Kc / 16, 256, 0, stream>>>(x, Xh, x2, cb, Eh, e2, N / 16);
        vq_gemm<<<(N / 128) * 4, 256, 0, stream>>>(Xh, Eh, e2, cand);
        vq_decide<<<N / 4, 256, 0, stream>>>(x, cb, cand, x2, e2, outq, outi);
    }
}

// Round 11
// 60.533 us; speedup vs baseline: 2.1179x; 1.0710x over previous
//
#include <hip/hip_runtime.h>

#define D 256

typedef __attribute__((ext_vector_type(8))) _Float16 f16x8;
typedef __attribute__((ext_vector_type(8))) short    s16x8;
typedef __attribute__((ext_vector_type(4))) float    f4_t;

// ---- merged conv: fp32 -> fp16 panel-permute + numpy-pairwise rowsq --------
// blocks [0,nx): x -> xh,x2 ; blocks [nx, nx+K/16): cb -> eh,e2
__global__ __launch_bounds__(256) void conv_all(
    const float* __restrict__ x, short* __restrict__ xh, float* __restrict__ x2,
    const float* __restrict__ cb, short* __restrict__ eh, float* __restrict__ e2,
    int nx) {
    __shared__ float tile[16 * 264];
    const int t = threadIdx.x;
    const int bid = blockIdx.x;
    const float* in; short* out; float* sq; int p;
    if (bid < nx) { in = x;  out = xh; sq = x2; p = bid; }
    else          { in = cb; out = eh; sq = e2; p = bid - nx; }
    const float* src = in + (size_t)p * 16 * 256;
#pragma unroll
    for (int it = 0; it < 4; ++it) {
        int idx = it * 256 + t;
        int row = idx >> 6, c4 = idx & 63;
        float4 v = *(const float4*)(src + row * 256 + c4 * 4);
        *(float4*)(tile + row * 264 + c4 * 4) = v;
    }
    __syncthreads();
    {   // rowsq: 16 threads/row, numpy pairwise order
        int row = t >> 4, lane = t & 15;
        int b = lane >> 3, j = lane & 7;
        const float* q = tile + row * 264 + b * 128 + j;
        float r = 0.f;
        {
#pragma clang fp contract(off)
            for (int i = 0; i < 16; ++i) { float v = q[8 * i]; float s2 = v * v; r = r + s2; }
        }
        r += __shfl_xor(r, 1); r += __shfl_xor(r, 2);
        r += __shfl_xor(r, 4); r += __shfl_xor(r, 8);
        if (lane == 0) sq[p * 16 + row] = r;
    }
#pragma unroll
    for (int jj = 0; jj < 2; ++jj) {
        int sl = jj * 256 + t;
        int s = sl >> 6, chunk = (sl >> 4) & 3, rr = sl & 15;
        const float* q = tile + rr * 264 + s * 32 + chunk * 8;
        s16x8 h8;
#pragma unroll
        for (int e = 0; e < 8; ++e) {
            _Float16 hv = (_Float16)q[e];
            h8[e] = (short)__builtin_bit_cast(unsigned short, hv);
        }
        *(s16x8*)(out + (size_t)p * 4096 + (size_t)sl * 8) = h8;
    }
}

// ---- main: 128 rows x 256 codes (quarter); R8-proven 2-barrier schedule ----
// 4 waves x 32 rows, A in registers. 4 LDS bufs (33KB -> 4 blocks/CU).
// Iteration s: STAGE(2s+2),(2s+3); vmcnt(4); [barrier; read 2s,2s+1; MFMA;
// fold; barrier]. Residency: panels 2s,2s+1 staged at s-1; after this iter's
// STAGE outstanding=8, vmcnt(4) drains exactly them; entry barrier => all
// waves' chunks resident. WAR: STAGE(2s+2) writes buf (2s-2)&3, read in
// superphase s-1, whose reads completed before s-1's END barrier (consumed
// by MFMA lgkmcnt pre-barrier) -- the R8-validated separation.
__global__ __launch_bounds__(256, 4) void vq_gemm(
    const short* __restrict__ Xh, const short* __restrict__ Eh,
    const float* __restrict__ e2, int* __restrict__ cand) {
    __shared__ short Bs[4 * 4096];              // 4 panel bufs x 8KB = 32KB
    __shared__ float e2s[256];
    const int tid = threadIdx.x;
    const int l = tid & 63;
    const int w = tid >> 6;
    const int rb = blockIdx.x & 255;
    const int q  = blockIdx.x >> 8;             // code quarter
    const int R0 = rb * 128;
    const int pcBase = q * 16;

#define STAGE(pp) do {                                                        \
    const short* g_ = Eh + (size_t)(pcBase + (pp)) * 4096 + w * 512 + l * 8;  \
    short* d_ = (short*)Bs + ((pp) & 3) * 4096 + w * 512;                     \
    __builtin_amdgcn_global_load_lds(                                         \
        (const __attribute__((address_space(1))) void*)g_,                    \
        (__attribute__((address_space(3))) void*)d_, 16, 0, 0);               \
    __builtin_amdgcn_global_load_lds(                                         \
        (const __attribute__((address_space(1))) void*)(g_ + 2048),           \
        (__attribute__((address_space(3))) void*)(d_ + 2048), 16, 0, 0);      \
} while (0)

    // A: wave's 32 rows x 256 k, 16 fragments in registers (loaded once)
    f16x8 aa[2][8];
#pragma unroll
    for (int m = 0; m < 2; ++m)
#pragma unroll
        for (int s = 0; s < 8; ++s)
            aa[m][s] = *(const f16x8*)(Xh +
                (size_t)((R0 >> 4) + w * 2 + m) * 4096 + s * 512 + l * 8);

    e2s[tid] = 0.5f * e2[q * 256 + tid] + 256.0f;

    STAGE(0); STAGE(1);                         // panels 0,1
    __syncthreads();                            // full drain + e2s visibility

    unsigned int k1[2][4], k2[2][4];
#pragma unroll
    for (int m = 0; m < 2; ++m)
#pragma unroll
        for (int r = 0; r < 4; ++r) { k1[m][r] = 0xFFFFFFFFu; k2[m][r] = 0xFFFFFFFFu; }

#define SPBODY(S)                                                             \
    __builtin_amdgcn_s_barrier();                                             \
    asm volatile("" ::: "memory");                                            \
    _Pragma("unroll")                                                         \
    for (int hp = 0; hp < 2; ++hp) {                                          \
        const int p = 2 * (S) + hp;                                           \
        const short* bp = (const short*)Bs + (p & 3) * 4096;                  \
        f4_t acc[2][2];                                                       \
        _Pragma("unroll")                                                     \
        for (int m = 0; m < 2; ++m) {                                         \
            f4_t z = {0.f,0.f,0.f,0.f}; acc[m][0] = z; acc[m][1] = z;         \
        }                                                                     \
        __builtin_amdgcn_s_setprio(1);                                        \
        {                                                                     \
            f16x8 bb[4];                                                      \
            _Pragma("unroll")                                                 \
            for (int k = 0; k < 4; ++k)                                       \
                bb[k] = *(const f16x8*)(bp + k * 512 + l * 8);                \
            _Pragma("unroll")                                                 \
            for (int k = 0; k < 4; ++k)                                       \
                _Pragma("unroll")                                             \
                for (int m = 0; m < 2; ++m)                                   \
                    acc[m][0] = __builtin_amdgcn_mfma_f32_16x16x32_f16(       \
                        aa[m][k], bb[k], acc[m][0], 0, 0, 0);                 \
        }                                                                     \
        {                                                                     \
            f16x8 bb[4];                                                      \
            _Pragma("unroll")                                                 \
            for (int k = 0; k < 4; ++k)                                       \
                bb[k] = *(const f16x8*)(bp + (k + 4) * 512 + l * 8);          \
            _Pragma("unroll")                                                 \
            for (int k = 0; k < 4; ++k)                                       \
                _Pragma("unroll")                                             \
                for (int m = 0; m < 2; ++m)                                   \
                    acc[m][1] = __builtin_amdgcn_mfma_f32_16x16x32_f16(       \
                        aa[m][k + 4], bb[k], acc[m][1], 0, 0, 0);             \
        }                                                                     \
        __builtin_amdgcn_s_setprio(0);                                        \
        const unsigned int code = (unsigned int)(q * 256 + p * 16 + (l & 15));\
        const float e2b = e2s[p * 16 + (l & 15)];                             \
        _Pragma("unroll")                                                     \
        for (int m = 0; m < 2; ++m)                                           \
            _Pragma("unroll")                                                 \
            for (int r = 0; r < 4; ++r) {                                     \
                float v = e2b - (acc[m][0][r] + acc[m][1][r]);                \
                unsigned int u = __builtin_bit_cast(unsigned int, v);         \
                unsigned int key = (u & 0xFFFFFC00u) | code;  /* v>233>0 */   \
                unsigned int mx = k1[m][r] > key ? k1[m][r] : key;            \
                k1[m][r] = k1[m][r] < key ? k1[m][r] : key;                   \
                k2[m][r] = k2[m][r] < mx ? k2[m][r] : mx;                     \
            }                                                                 \
    }                                                                         \
    __builtin_amdgcn_s_barrier();                                             \
    asm volatile("" ::: "memory");

#pragma unroll 1
    for (int s = 0; s < 7; ++s) {               // stage 1 superphase ahead
        STAGE(2 * s + 2); STAGE(2 * s + 3);
        asm volatile("s_waitcnt vmcnt(4)" ::: "memory");
        SPBODY(s)
    }
    {                                           // tail: nothing left to stage
        asm volatile("s_waitcnt vmcnt(0)" ::: "memory");
        SPBODY(7)
    }

    // top-2 reduce across the 16 lanes sharing each row; write candidates
    {
        int q4 = l >> 4;
#pragma unroll
        for (int m = 0; m < 2; ++m)
#pragma unroll
            for (int r = 0; r < 4; ++r) {
                unsigned int a = k1[m][r], b = k2[m][r];
#pragma unroll
                for (int msk = 1; msk < 16; msk <<= 1) {
                    unsigned int oa = __shfl_xor(a, msk);
                    unsigned int ob = __shfl_xor(b, msk);
                    unsigned int hi_ = a > oa ? a : oa;
                    a = a < oa ? a : oa;
                    b = b < ob ? b : ob;
                    b = b < hi_ ? b : hi_;
                }
                if ((l & 15) == 0) {
                    int row = R0 + w * 32 + m * 16 + q4 * 4 + r;
                    int2 o; o.x = (int)(a & 1023u); o.y = (int)(b & 1023u);
                    *(int2*)(cand + (size_t)row * 8 + q * 2) = o;
                }
            }
    }
#undef SPBODY
#undef STAGE
}

// ---- exact fp32 recheck of 8 candidates (ref formula + tie-break) + gather --
__global__ __launch_bounds__(256) void vq_decide(const float* __restrict__ x,
    const float* __restrict__ cb, const int* __restrict__ cand,
    const float* __restrict__ x2, const float* __restrict__ e2,
    float* __restrict__ outq, float* __restrict__ outi) {
    const int w = threadIdx.x >> 6, l = threadIdx.x & 63;
    const int row = blockIdx.x * 4 + w;
    const int o = l >> 3, j = l & 7;
    const int c = cand[(size_t)row * 8 + o];
    const float4* xr = (const float4*)(x + (size_t)row * D);
    const float4* er = (const float4*)(cb + (size_t)c * D);
    float xe = 0.f;
#pragma unroll
    for (int i = 0; i < 8; ++i) {
        float4 xv = xr[i * 8 + j], ev = er[i * 8 + j];
        xe = fmaf(xv.x, ev.x, xe); xe = fmaf(xv.y, ev.y, xe);
        xe = fmaf(xv.z, ev.z, xe); xe = fmaf(xv.w, ev.w, xe);
    }
    xe += __shfl_xor(xe, 1); xe += __shfl_xor(xe, 2); xe += __shfl_xor(xe, 4);
    float s0 = x2[row] + e2[c];                 // ref order: (x2 + e2) first
    float dist = s0 - 2.f * xe;                 // then - 2*xe
    float best = 3.4e38f; int bi = 0x7fffffff;
#pragma unroll
    for (int oq = 0; oq < 8; ++oq) {
        float dd = __shfl(dist, oq * 8);
        int   ii = __shfl(c,    oq * 8);
        if (dd < best || (dd == best && ii < bi)) { best = dd; bi = ii; }
    }
    float4 v = ((const float4*)(cb + (size_t)bi * D))[l];
    ((float4*)(outq + (size_t)row * D))[l] = v;
    if (l == 0) outi[row] = (float)bi;
}

extern "C" void kernel_launch(void* const* d_in, const int* in_sizes, int n_in,
                              void* d_out, int out_size, void* d_ws, size_t ws_size,
                              hipStream_t stream) {
    const float* x  = (const float*)d_in[0];
    const float* cb = (const float*)d_in[1];
    const int N  = in_sizes[0] / D;   // 32768
    const int Kc = in_sizes[1] / D;   // 1024

    float* outq = (float*)d_out;
    float* outi = outq + (size_t)N * D;

    const size_t needX = (size_t)N * D * 2;                        // 16 MB
    const size_t needS = (size_t)Kc * D * 2 + (size_t)Kc * 4
                       + (size_t)N * 4 + (size_t)N * 8 * 4;        // ~1.7 MB

    short* Xh; char* small;
    if (ws_size >= needX + needS) {
        Xh = (short*)d_ws;
        small = (char*)d_ws + needX;
    } else {
        // Xh lives in d_out[0,16MB). gemm reads it; vq_decide overwrites that
        // region with outq only after gemm completes (stream order). outi is
        // the last 128 KB of d_out -- no overlap.
        Xh = (short*)d_out;
        small = (char*)d_ws;
    }
    short* Eh  = (short*)small;
    float* e2  = (float*)(Eh + (size_t)Kc * D);
    float* x2  = e2 + Kc;
    int*  cand = (int*)(x2 + N);

    conv_all<<<N / 16 + Kc / 16, 256, 0, stream>>>(x, Xh, x2, cb, Eh, e2, N / 16);
    vq_gemm<<<(N / 128) * 4, 256, 0, stream>>>(Xh, Eh, e2, cand);
    vq_decide<<<N / 4, 256, 0, stream>>>(x, cb, cand, x2, e2, outq, outi);
}